// Round 1
// baseline (827.400 us; speedup 1.0000x reference)
//
#include <hip/hip_runtime.h>
#include <cfloat>
#include <cmath>

// Problem constants
#define NB 32           // B
#define NN 8            // N codebooks
#define NM 512          // M codes
#define ND 32           // D dim
#define NHW 1024        // H*W
#define NC 256          // C = N*D
#define NCHW (NC * NHW) // 262144
#define NL (NB * NHW)   // 32768 points per codebook

static constexpr double DECAY_D = 0.999;
static constexpr float DECAYF = (float)DECAY_D;
static constexpr float OMDF = (float)(1.0 - DECAY_D);       // matches python 1.0-0.999 -> fp32
static constexpr float EPSF = 1e-5f;
static constexpr float MEPSF = (float)(512.0 * 1e-5);       // M * EPS
static constexpr float LOSS_SCALE = (float)(0.25 / (double)(NB * (size_t)NC * NHW));

// Workspace layout (floats)
#define WS_COUNTS 0
#define WS_DW (NN * NM)                  // 4096
#define WS_E2 (WS_DW + NN * NM * ND)     // 135168
// Output layout (floats)
#define OUT_X 0
#define OUT_LOSS (NB * NC * NHW)         // 8388608
#define OUT_PERP (OUT_LOSS + 1)
#define OUT_EMB (OUT_PERP + 1)           // 8388610
#define OUT_CNT (OUT_EMB + NN * NM * ND) // 8519682
#define OUT_W (OUT_CNT + NN * NM)        // 8523778

__global__ void e2_kernel(const float* __restrict__ emb, float* __restrict__ e2) {
    int i = blockIdx.x * 256 + threadIdx.x; // 0..4095 over (n,m)
    const float* e = emb + i * ND;
    float s0 = 0.f, s1 = 0.f, s2 = 0.f, s3 = 0.f;
#pragma unroll
    for (int d = 0; d < ND; d += 4) {
        s0 = fmaf(e[d], e[d], s0);
        s1 = fmaf(e[d + 1], e[d + 1], s1);
        s2 = fmaf(e[d + 2], e[d + 2], s2);
        s3 = fmaf(e[d + 3], e[d + 3], s3);
    }
    e2[i] = (s0 + s1) + (s2 + s3);
}

__launch_bounds__(256, 2)
__global__ void vq_main(const float* __restrict__ x, const float* __restrict__ emb,
                        const float* __restrict__ e2g, float* __restrict__ out,
                        float* __restrict__ counts, float* __restrict__ dw,
                        float* __restrict__ loss_out) {
    __shared__ float se[NM * ND];  // 64 KB: embedding[n]
    __shared__ float se2[NM];      // 2 KB
    __shared__ float red[4];

    const int n = blockIdx.y;
    const int tid = threadIdx.x;

    const float* en = emb + n * NM * ND;
    for (int i = tid; i < NM * ND; i += 256) se[i] = en[i];
    for (int i = tid; i < NM; i += 256) se2[i] = e2g[n * NM + i];
    __syncthreads();

    // two points per thread: la, lb
    const int l_base = blockIdx.x * 512;
    const int la = l_base + tid;
    const int lb = l_base + 256 + tid;
    const int bia_ = la >> 10, bib_ = lb >> 10;      // batch index
    const int pa = la & (NHW - 1), pb = lb & (NHW - 1);
    const float* xpa = x + (size_t)bia_ * NCHW + n * ND * NHW + pa;
    const float* xpb = x + (size_t)bib_ * NCHW + n * ND * NHW + pb;

    float xa[ND], xb[ND];
#pragma unroll
    for (int d = 0; d < ND; ++d) {
        xa[d] = xpa[d * NHW];
        xb[d] = xpb[d * NHW];
    }

    float s0 = 0.f, s1 = 0.f, s2 = 0.f, s3 = 0.f;
    float t0 = 0.f, t1 = 0.f, t2 = 0.f, t3 = 0.f;
#pragma unroll
    for (int d = 0; d < ND; d += 4) {
        s0 = fmaf(xa[d], xa[d], s0);
        s1 = fmaf(xa[d + 1], xa[d + 1], s1);
        s2 = fmaf(xa[d + 2], xa[d + 2], s2);
        s3 = fmaf(xa[d + 3], xa[d + 3], s3);
        t0 = fmaf(xb[d], xb[d], t0);
        t1 = fmaf(xb[d + 1], xb[d + 1], t1);
        t2 = fmaf(xb[d + 2], xb[d + 2], t2);
        t3 = fmaf(xb[d + 3], xb[d + 3], t3);
    }
    const float x2a = (s0 + s1) + (s2 + s3);
    const float x2b = (t0 + t1) + (t2 + t3);

    float best_a = FLT_MAX, best_b = FLT_MAX;
    int ia = 0, ib = 0;
    for (int m = 0; m < NM; ++m) {
        const float* em = se + m * ND;
        float a0 = 0.f, a1 = 0.f, a2 = 0.f, a3 = 0.f;
        float b0 = 0.f, b1 = 0.f, b2 = 0.f, b3 = 0.f;
#pragma unroll
        for (int d = 0; d < ND; d += 4) {
            const float e0 = em[d], e1 = em[d + 1], e2_ = em[d + 2], e3 = em[d + 3];
            a0 = fmaf(xa[d], e0, a0);
            a1 = fmaf(xa[d + 1], e1, a1);
            a2 = fmaf(xa[d + 2], e2_, a2);
            a3 = fmaf(xa[d + 3], e3, a3);
            b0 = fmaf(xb[d], e0, b0);
            b1 = fmaf(xb[d + 1], e1, b1);
            b2 = fmaf(xb[d + 2], e2_, b2);
            b3 = fmaf(xb[d + 3], e3, b3);
        }
        const float dota = (a0 + a1) + (a2 + a3);
        const float dotb = (b0 + b1) + (b2 + b3);
        const float da = (se2[m] + x2a) - 2.0f * dota;
        const float db = (se2[m] + x2b) - 2.0f * dotb;
        if (da < best_a) { best_a = da; ia = m; }
        if (db < best_b) { best_b = db; ib = m; }
    }

    // quantized output + loss
    float* outa = out + (size_t)bia_ * NCHW + n * ND * NHW + pa;
    float* outb = out + (size_t)bib_ * NCHW + n * ND * NHW + pb;
    const float* ea = se + ia * ND;
    const float* eb = se + ib * ND;
    float loss_acc = 0.f;
#pragma unroll
    for (int d = 0; d < ND; ++d) {
        const float qa = ea[d];
        outa[d * NHW] = qa;
        const float da = xa[d] - qa;
        loss_acc = fmaf(da, da, loss_acc);
    }
#pragma unroll
    for (int d = 0; d < ND; ++d) {
        const float qb = eb[d];
        outb[d * NHW] = qb;
        const float db = xb[d] - qb;
        loss_acc = fmaf(db, db, loss_acc);
    }

    // scatter: counts and dw
    atomicAdd(&counts[n * NM + ia], 1.0f);
    atomicAdd(&counts[n * NM + ib], 1.0f);
    float* dwa = dw + (size_t)(n * NM + ia) * ND;
    float* dwb = dw + (size_t)(n * NM + ib) * ND;
#pragma unroll
    for (int d = 0; d < ND; ++d) atomicAdd(&dwa[d], xa[d]);
#pragma unroll
    for (int d = 0; d < ND; ++d) atomicAdd(&dwb[d], xb[d]);

    // block loss reduction
#pragma unroll
    for (int off = 32; off; off >>= 1) loss_acc += __shfl_down(loss_acc, off);
    if ((tid & 63) == 0) red[tid >> 6] = loss_acc;
    __syncthreads();
    if (tid == 0) {
        const float s = (red[0] + red[1]) + (red[2] + red[3]);
        atomicAdd(loss_out, s * LOSS_SCALE);
    }
}

__global__ void vq_update_cnt(const float* __restrict__ ema_count,
                              const float* __restrict__ counts,
                              float* __restrict__ out_cnt,
                              float* __restrict__ perp_out) {
    const int n = blockIdx.x;
    const int m = threadIdx.x; // 512 threads
    __shared__ float r1[8], r2[8];
    __shared__ float s_ntot;

    const float cnt = counts[n * NM + m];
    const float cnew = DECAYF * ema_count[n * NM + m] + OMDF * cnt;

    const float avg = cnt / (float)NL;
    const float pterm = avg * logf(avg + 1e-10f);

    float v1 = cnew, v2 = pterm;
#pragma unroll
    for (int off = 32; off; off >>= 1) {
        v1 += __shfl_down(v1, off);
        v2 += __shfl_down(v2, off);
    }
    if ((m & 63) == 0) { r1[m >> 6] = v1; r2[m >> 6] = v2; }
    __syncthreads();
    if (m == 0) {
        float a = 0.f, b = 0.f;
#pragma unroll
        for (int i = 0; i < 8; ++i) { a += r1[i]; b += r2[i]; }
        s_ntot = a;
        atomicAdd(perp_out, expf(-b));
    }
    __syncthreads();
    const float ntot = s_ntot;
    const float cadj = (cnew + EPSF) / (ntot + MEPSF) * ntot;
    out_cnt[n * NM + m] = cadj;
}

__global__ void vq_update_w(const float* __restrict__ ema_weight,
                            const float* __restrict__ dw,
                            const float* __restrict__ out_cnt,
                            float* __restrict__ out_w,
                            float* __restrict__ out_emb) {
    const int i = blockIdx.x * 256 + threadIdx.x; // over N*M*D = 131072
    const float wnew = DECAYF * ema_weight[i] + OMDF * dw[i];
    out_w[i] = wnew;
    out_emb[i] = wnew / out_cnt[i >> 5];
}

extern "C" void kernel_launch(void* const* d_in, const int* in_sizes, int n_in,
                              void* d_out, int out_size, void* d_ws, size_t ws_size,
                              hipStream_t stream) {
    const float* x = (const float*)d_in[0];
    const float* emb = (const float*)d_in[1];
    const float* ema_count = (const float*)d_in[2];
    const float* ema_weight = (const float*)d_in[3];
    float* out = (float*)d_out;
    float* ws = (float*)d_ws;

    float* counts = ws + WS_COUNTS;
    float* dw = ws + WS_DW;
    float* e2 = ws + WS_E2;

    // zero accumulators (re-poisoned to 0xAA before every timed launch)
    hipMemsetAsync(counts, 0, (size_t)(NN * NM + NN * NM * ND) * sizeof(float), stream);
    hipMemsetAsync(out + OUT_LOSS, 0, 2 * sizeof(float), stream);

    e2_kernel<<<(NN * NM) / 256, 256, 0, stream>>>(emb, e2);

    dim3 grid(NL / 512, NN);
    vq_main<<<grid, 256, 0, stream>>>(x, emb, e2, out, counts, dw, out + OUT_LOSS);

    vq_update_cnt<<<NN, NM, 0, stream>>>(ema_count, counts, out + OUT_CNT, out + OUT_PERP);
    vq_update_w<<<(NN * NM * ND) / 256, 256, 0, stream>>>(ema_weight, dw, out + OUT_CNT,
                                                          out + OUT_EMB, out + OUT_W);
}

// Round 3
// 207.855 us; speedup vs baseline: 3.9807x; 3.9807x over previous
//
#include <hip/hip_runtime.h>
#include <cfloat>
#include <cmath>

// Problem constants
#define NB 32           // B
#define NN 8            // N codebooks
#define NM 512          // M codes
#define ND 32           // D dim
#define NHW 1024        // H*W
#define NC 256          // C = N*D
#define NCHW (NC * NHW) // 262144
#define NL (NB * NHW)   // 32768 points per codebook
#define EPAD 40         // padded bf16 row (80 B)
#define XPAD 33         // padded fp32 row for x / dw staging

static constexpr float DECAYF = (float)0.999;
static constexpr float OMDF = (float)(1.0 - 0.999);
static constexpr float EPSF = 1e-5f;
static constexpr float MEPSF = (float)(512.0 * 1e-5);
static constexpr float LOSS_SCALE = (float)(0.25 / 8388608.0);

// Output layout (floats)
#define OUT_LOSS (NB * NC * NHW)         // 8388608
#define OUT_PERP (OUT_LOSS + 1)
#define OUT_EMB (OUT_PERP + 1)
#define OUT_CNT (OUT_EMB + NN * NM * ND)
#define OUT_W (OUT_CNT + NN * NM)

typedef __attribute__((ext_vector_type(8))) short bf16x8;
typedef __attribute__((ext_vector_type(4))) float f32x4;

__device__ inline unsigned short f2bf(float f) {
    unsigned u = __builtin_bit_cast(unsigned, f);
    u += 0x7FFFu + ((u >> 16) & 1u);
    return (unsigned short)(u >> 16);
}
__device__ inline float bf2f(unsigned short h) {
    unsigned u = ((unsigned)h) << 16;
    return __builtin_bit_cast(float, u);
}

// ---- K1: embedding prep: bf16 hi/lo split (padded rows) + e2 ----
__global__ void e_prep(const float* __restrict__ emb, unsigned short* __restrict__ ehi,
                       unsigned short* __restrict__ elo, float* __restrict__ e2) {
    const int i = blockIdx.x * 256 + threadIdx.x; // (n*512 + m), 4096 total
    const float* e = emb + i * ND;
    unsigned short* hi = ehi + (size_t)i * EPAD;
    unsigned short* lo = elo + (size_t)i * EPAD;
    float s = 0.f;
#pragma unroll
    for (int d = 0; d < ND; ++d) {
        const float v = e[d];
        s = fmaf(v, v, s);
        const unsigned short h = f2bf(v);
        hi[d] = h;
        lo[d] = f2bf(v - bf2f(h));
    }
    e2[i] = s;
}

// ---- K2: MFMA distances + argmin + quantized output + loss ----
__launch_bounds__(256, 2)
__global__ void vq_argmin(const float* __restrict__ x,
                          const unsigned short* __restrict__ ehi,
                          const unsigned short* __restrict__ elo,
                          const float* __restrict__ e2g,
                          const float* __restrict__ emb,
                          float* __restrict__ out,
                          unsigned short* __restrict__ idx_out,
                          float* __restrict__ loss_out) {
    __shared__ __align__(16) unsigned short shi[256 * EPAD]; // 20480 B (half of codes)
    __shared__ __align__(16) unsigned short slo[256 * EPAD]; // 20480 B
    __shared__ float se2[NM];                                // 2048 B
    __shared__ __align__(16) float sx[256 * XPAD];           // 33792 B
    __shared__ unsigned short sidx[256];
    __shared__ float red[4];

    const int n = blockIdx.y;
    const int lbase = blockIdx.x * 256;
    const int tid = threadIdx.x;
    const int b = lbase >> 10;
    const int hw0 = lbase & (NHW - 1);

    // stage x tile: [256 points][32 d] fp32, padded
    {
        const float* xp = x + (size_t)b * NCHW + n * ND * NHW + hw0 + tid;
#pragma unroll
        for (int d = 0; d < ND; ++d)
            sx[tid * XPAD + d] = xp[d * NHW];
    }
    for (int i = tid; i < NM; i += 256) se2[i] = e2g[n * NM + i];
    __syncthreads();

    const int lane = tid & 63;
    const int w = tid >> 6;
    const int j16 = lane & 15;   // row (A) / col (B) index
    const int kg = lane >> 4;    // k-group

    // A fragments: 4 ltiles x 8 bf16, hi/lo split
    bf16x8 ah[4], al[4];
#pragma unroll
    for (int lt = 0; lt < 4; ++lt) {
        const int row = w * 64 + lt * 16 + j16;
        const float* sr = &sx[row * XPAD + kg * 8];
#pragma unroll
        for (int j = 0; j < 8; ++j) {
            const float v = sr[j];
            const unsigned short h = f2bf(v);
            ah[lt][j] = (short)h;
            al[lt][j] = (short)f2bf(v - bf2f(h));
        }
    }

    float bd[4][4];
    int bm[4][4];
#pragma unroll
    for (int lt = 0; lt < 4; ++lt)
#pragma unroll
        for (int r = 0; r < 4; ++r) { bd[lt][r] = FLT_MAX; bm[lt][r] = 0; }

    for (int half = 0; half < 2; ++half) {
        __syncthreads(); // previous half's LDS reads done
        {
            const unsigned* srch = (const unsigned*)(ehi + ((size_t)n * NM + half * 256) * EPAD);
            const unsigned* srcl = (const unsigned*)(elo + ((size_t)n * NM + half * 256) * EPAD);
            unsigned* dsth = (unsigned*)shi;
            unsigned* dstl = (unsigned*)slo;
            for (int i = tid; i < 256 * EPAD / 2; i += 256) {
                dsth[i] = srch[i];
                dstl[i] = srcl[i];
            }
        }
        __syncthreads();

        for (int mt = 0; mt < 16; ++mt) {
            const int mloc = mt * 16 + j16;
            const bf16x8 bh = *(const bf16x8*)&shi[mloc * EPAD + kg * 8];
            const bf16x8 bl = *(const bf16x8*)&slo[mloc * EPAD + kg * 8];
            const int mglob = half * 256 + mloc;
            const float e2v = se2[mglob];
#pragma unroll
            for (int lt = 0; lt < 4; ++lt) {
                f32x4 c = {0.f, 0.f, 0.f, 0.f};
                c = __builtin_amdgcn_mfma_f32_16x16x32_bf16(ah[lt], bh, c, 0, 0, 0);
                c = __builtin_amdgcn_mfma_f32_16x16x32_bf16(al[lt], bh, c, 0, 0, 0);
                c = __builtin_amdgcn_mfma_f32_16x16x32_bf16(ah[lt], bl, c, 0, 0, 0);
#pragma unroll
                for (int r = 0; r < 4; ++r) {
                    const float dist = fmaf(-2.f, c[r], e2v);
                    if (dist < bd[lt][r]) { bd[lt][r] = dist; bm[lt][r] = mglob; }
                }
            }
        }
    }

    // reduce over the 16 lanes (cols) of each group; tie -> lower m (np.argmin)
#pragma unroll
    for (int lt = 0; lt < 4; ++lt)
#pragma unroll
        for (int r = 0; r < 4; ++r) {
            float d0 = bd[lt][r];
            int m0 = bm[lt][r];
#pragma unroll
            for (int off = 1; off < 16; off <<= 1) {
                const float dn = __shfl_xor(d0, off, 64);
                const int mn = __shfl_xor(m0, off, 64);
                if (dn < d0 || (dn == d0 && mn < m0)) { d0 = dn; m0 = mn; }
            }
            bd[lt][r] = d0;
            bm[lt][r] = m0;
        }
    if (j16 == 0) {
#pragma unroll
        for (int lt = 0; lt < 4; ++lt)
#pragma unroll
            for (int r = 0; r < 4; ++r)
                sidx[w * 64 + lt * 16 + kg * 4 + r] = (unsigned short)bm[lt][r];
    }
    __syncthreads();

    // epilogue: idx write, quantized out, exact fp32 loss
    const unsigned m = sidx[tid];
    idx_out[n * NL + lbase + tid] = (unsigned short)m;
    const float* q = emb + ((size_t)n * NM + m) * ND;
    float* op = out + (size_t)b * NCHW + n * ND * NHW + hw0 + tid;
    float lacc = 0.f;
#pragma unroll
    for (int d0 = 0; d0 < ND; d0 += 4) {
        const float4 qv = *(const float4*)&q[d0];
        float xd, df;
        xd = sx[tid * XPAD + d0 + 0]; op[(d0 + 0) * NHW] = qv.x; df = xd - qv.x; lacc = fmaf(df, df, lacc);
        xd = sx[tid * XPAD + d0 + 1]; op[(d0 + 1) * NHW] = qv.y; df = xd - qv.y; lacc = fmaf(df, df, lacc);
        xd = sx[tid * XPAD + d0 + 2]; op[(d0 + 2) * NHW] = qv.z; df = xd - qv.z; lacc = fmaf(df, df, lacc);
        xd = sx[tid * XPAD + d0 + 3]; op[(d0 + 3) * NHW] = qv.w; df = xd - qv.w; lacc = fmaf(df, df, lacc);
    }
#pragma unroll
    for (int off = 32; off; off >>= 1) lacc += __shfl_down(lacc, off);
    if (lane == 0) red[w] = lacc;
    __syncthreads();
    if (tid == 0)
        atomicAdd(loss_out, (red[0] + red[1] + red[2] + red[3]) * LOSS_SCALE);
}

// ---- K3: counts/dw scatter: LDS accumulate per (n,b), one global atomic per cell ----
__launch_bounds__(256, 2)
__global__ void vq_scatter(const float* __restrict__ x,
                           const unsigned short* __restrict__ idx,
                           float* __restrict__ dw, float* __restrict__ counts) {
    __shared__ float sdw[NM * XPAD]; // 67584 B
    __shared__ float scnt[NM];
    const int n = blockIdx.y;
    const int b = blockIdx.x; // one batch per block
    const int tid = threadIdx.x;
    for (int i = tid; i < NM * XPAD; i += 256) sdw[i] = 0.f;
    for (int i = tid; i < NM; i += 256) scnt[i] = 0.f;
    __syncthreads();

    const float* xp = x + (size_t)b * NCHW + n * ND * NHW;
#pragma unroll
    for (int it = 0; it < 4; ++it) {
        const int hw = it * 256 + tid;
        const unsigned m = idx[n * NL + b * NHW + hw];
        float* dst = &sdw[m * XPAD];
#pragma unroll
        for (int d = 0; d < ND; ++d)
            atomicAdd(&dst[d], xp[d * NHW + hw]);
        atomicAdd(&scnt[m], 1.0f);
    }
    __syncthreads();

    float* dwn = dw + (size_t)n * NM * ND;
    for (int i = tid; i < NM * ND; i += 256)
        atomicAdd(&dwn[i], sdw[(i >> 5) * XPAD + (i & 31)]);
    float* cn = counts + n * NM;
    for (int i = tid; i < NM; i += 256) atomicAdd(&cn[i], scnt[i]);
}

// ---- K4a: EMA count update + perplexity ----
__global__ void vq_update_cnt(const float* __restrict__ ema_count,
                              const float* __restrict__ counts,
                              float* __restrict__ out_cnt,
                              float* __restrict__ perp_out) {
    const int n = blockIdx.x;
    const int m = threadIdx.x; // 512
    __shared__ float r1[8], r2[8];
    __shared__ float s_ntot;

    const float cnt = counts[n * NM + m];
    const float cnew = DECAYF * ema_count[n * NM + m] + OMDF * cnt;
    const float avg = cnt / (float)NL;
    const float pterm = avg * logf(avg + 1e-10f);

    float v1 = cnew, v2 = pterm;
#pragma unroll
    for (int off = 32; off; off >>= 1) {
        v1 += __shfl_down(v1, off);
        v2 += __shfl_down(v2, off);
    }
    if ((m & 63) == 0) { r1[m >> 6] = v1; r2[m >> 6] = v2; }
    __syncthreads();
    if (m == 0) {
        float a = 0.f, bsum = 0.f;
#pragma unroll
        for (int i = 0; i < 8; ++i) { a += r1[i]; bsum += r2[i]; }
        s_ntot = a;
        atomicAdd(perp_out, expf(-bsum));
    }
    __syncthreads();
    const float ntot = s_ntot;
    out_cnt[n * NM + m] = (cnew + EPSF) / (ntot + MEPSF) * ntot;
}

// ---- K4b: EMA weight + embedding_new ----
__global__ void vq_update_w(const float* __restrict__ ema_weight,
                            const float* __restrict__ dw,
                            const float* __restrict__ out_cnt,
                            float* __restrict__ out_w,
                            float* __restrict__ out_emb) {
    const int i = blockIdx.x * 256 + threadIdx.x; // 131072
    const float wnew = DECAYF * ema_weight[i] + OMDF * dw[i];
    out_w[i] = wnew;
    out_emb[i] = wnew / out_cnt[i >> 5];
}

extern "C" void kernel_launch(void* const* d_in, const int* in_sizes, int n_in,
                              void* d_out, int out_size, void* d_ws, size_t ws_size,
                              hipStream_t stream) {
    const float* x = (const float*)d_in[0];
    const float* emb = (const float*)d_in[1];
    const float* ema_count = (const float*)d_in[2];
    const float* ema_weight = (const float*)d_in[3];
    float* out = (float*)d_out;
    char* ws = (char*)d_ws;
    float* ws_f = (float*)d_ws;

    // ws layout (bytes), total ~1.74 MB
    float* counts = ws_f;                                   // [0, 16384)
    float* dw = ws_f + 4096;                                // [16384, 540672)
    float* e2 = ws_f + 135168;                              // [540672, 557056)
    unsigned short* ehi = (unsigned short*)(ws + 557056);   // 327,680 B
    unsigned short* elo = (unsigned short*)(ws + 884736);   // 327,680 B
    unsigned short* idxp = (unsigned short*)(ws + 1212416); // 524,288 B

    // zero accumulators (buffers are re-poisoned to 0xAA before every timed launch)
    hipMemsetAsync(counts, 0, (size_t)(NN * NM + NN * NM * ND) * sizeof(float), stream);
    hipMemsetAsync(out + OUT_LOSS, 0, 2 * sizeof(float), stream);

    e_prep<<<16, 256, 0, stream>>>(emb, ehi, elo, e2);
    vq_argmin<<<dim3(NL / 256, NN), 256, 0, stream>>>(x, ehi, elo, e2, emb, out, idxp,
                                                      out + OUT_LOSS);
    vq_scatter<<<dim3(NB, NN), 256, 0, stream>>>(x, idxp, dw, counts);
    vq_update_cnt<<<NN, NM, 0, stream>>>(ema_count, counts, out + OUT_CNT, out + OUT_PERP);
    vq_update_w<<<NN * NM * ND / 256, 256, 0, stream>>>(ema_weight, dw, out + OUT_CNT,
                                                        out + OUT_EMB, out + OUT_W);
}

// Round 6
// 197.876 us; speedup vs baseline: 4.1814x; 1.0504x over previous
//
#include <hip/hip_runtime.h>
#include <cfloat>
#include <cmath>

// Problem constants
#define NB 32           // B
#define NN 8            // N codebooks
#define NM 512          // M codes
#define ND 32           // D dim
#define NHW 1024        // H*W
#define NC 256          // C = N*D
#define NCHW (NC * NHW) // 262144
#define NL (NB * NHW)   // 32768 points per codebook
#define EPAD 40         // padded bf16 row (80 B)
#define XPAD 33         // padded fp32 row for x / dw staging

static constexpr float DECAYF = (float)0.999;
static constexpr float OMDF = (float)(1.0 - 0.999);
static constexpr float EPSF = 1e-5f;
static constexpr float MEPSF = (float)(512.0 * 1e-5);
static constexpr float LOSS_SCALE = (float)(0.25 / 8388608.0);

// Output layout (floats)
#define OUT_LOSS (NB * NC * NHW)         // 8388608
#define OUT_PERP (OUT_LOSS + 1)
#define OUT_EMB (OUT_PERP + 1)
#define OUT_CNT (OUT_EMB + NN * NM * ND)
#define OUT_W (OUT_CNT + NN * NM)

typedef __attribute__((ext_vector_type(8))) short bf16x8;
typedef __attribute__((ext_vector_type(4))) float f32x4;

__device__ inline unsigned short f2bf(float f) {
    unsigned u = __builtin_bit_cast(unsigned, f);
    u += 0x7FFFu + ((u >> 16) & 1u);
    return (unsigned short)(u >> 16);
}
__device__ inline float bf2f(unsigned short h) {
    unsigned u = ((unsigned)h) << 16;
    return __builtin_bit_cast(float, u);
}

// ---- K1: embedding prep: bf16 hi/lo split (padded rows) + e2 ----
__global__ void e_prep(const float* __restrict__ emb, unsigned short* __restrict__ ehi,
                       unsigned short* __restrict__ elo, float* __restrict__ e2) {
    const int i = blockIdx.x * 256 + threadIdx.x; // (n*512 + m), 4096 total
    const float* e = emb + i * ND;
    unsigned short* hi = ehi + (size_t)i * EPAD;
    unsigned short* lo = elo + (size_t)i * EPAD;
    float s = 0.f;
#pragma unroll
    for (int d = 0; d < ND; ++d) {
        const float v = e[d];
        s = fmaf(v, v, s);
        const unsigned short h = f2bf(v);
        hi[d] = h;
        lo[d] = f2bf(v - bf2f(h));
    }
    e2[i] = s;
}

// ---- K2: MFMA distances + argmin + quantized output + loss ----
// Codes are read as B-fragments straight from global (L2-resident, 640 KB);
// LDS holds only the x tile -> ~36 KB -> 4 blocks/CU.
__launch_bounds__(256, 4)
__global__ void vq_argmin(const float* __restrict__ x,
                          const unsigned short* __restrict__ ehi,
                          const unsigned short* __restrict__ elo,
                          const float* __restrict__ e2g,
                          const float* __restrict__ emb,
                          float* __restrict__ out,
                          unsigned short* __restrict__ idx_out,
                          float* __restrict__ loss_out) {
    __shared__ __align__(16) float sx[256 * XPAD];           // 33792 B
    __shared__ float se2[NM];                                // 2048 B
    __shared__ unsigned short sidx[256];
    __shared__ float red[4];

    const int n = blockIdx.y;
    const int lbase = blockIdx.x * 256;
    const int tid = threadIdx.x;
    const int b = lbase >> 10;
    const int hw0 = lbase & (NHW - 1);

    // stage x tile: [256 points][32 d] fp32, padded (bank-conflict-free writes)
    {
        const float* xp = x + (size_t)b * NCHW + n * ND * NHW + hw0 + tid;
#pragma unroll
        for (int d = 0; d < ND; ++d)
            sx[tid * XPAD + d] = xp[d * NHW];
    }
    for (int i = tid; i < NM; i += 256) se2[i] = e2g[n * NM + i];
    __syncthreads();

    const int lane = tid & 63;
    const int w = tid >> 6;
    const int j16 = lane & 15;   // row (A) / col (B) index
    const int kg = lane >> 4;    // k-group

    // A fragments: 4 ltiles x 8 bf16, hi/lo split
    bf16x8 ah[4], al[4];
#pragma unroll
    for (int lt = 0; lt < 4; ++lt) {
        const int row = w * 64 + lt * 16 + j16;
        const float* sr = &sx[row * XPAD + kg * 8];
#pragma unroll
        for (int j = 0; j < 8; ++j) {
            const float v = sr[j];
            const unsigned short h = f2bf(v);
            ah[lt][j] = (short)h;
            al[lt][j] = (short)f2bf(v - bf2f(h));
        }
    }

    float bd[4][4];
    int bm[4][4];
#pragma unroll
    for (int lt = 0; lt < 4; ++lt)
#pragma unroll
        for (int r = 0; r < 4; ++r) { bd[lt][r] = FLT_MAX; bm[lt][r] = 0; }

    // B-fragment base for this lane: code row (n*512 + j16), d-slice kg*8
    const unsigned short* bh_base = ehi + ((size_t)n * NM + j16) * EPAD + kg * 8;
    const unsigned short* bl_base = elo + ((size_t)n * NM + j16) * EPAD + kg * 8;

    // 1-deep software pipeline over 32 m-tiles
    bf16x8 bh = *(const bf16x8*)(bh_base);
    bf16x8 bl = *(const bf16x8*)(bl_base);
    for (int mt = 0; mt < 32; ++mt) {
        const bf16x8 cbh = bh, cbl = bl;
        if (mt < 31) {
            bh = *(const bf16x8*)(bh_base + (size_t)(mt + 1) * 16 * EPAD);
            bl = *(const bf16x8*)(bl_base + (size_t)(mt + 1) * 16 * EPAD);
        }
        const int mloc = mt * 16 + j16;
        const float e2v = se2[mloc];
#pragma unroll
        for (int lt = 0; lt < 4; ++lt) {
            f32x4 c = {0.f, 0.f, 0.f, 0.f};
            c = __builtin_amdgcn_mfma_f32_16x16x32_bf16(ah[lt], cbh, c, 0, 0, 0);
            c = __builtin_amdgcn_mfma_f32_16x16x32_bf16(al[lt], cbh, c, 0, 0, 0);
            c = __builtin_amdgcn_mfma_f32_16x16x32_bf16(ah[lt], cbl, c, 0, 0, 0);
#pragma unroll
            for (int r = 0; r < 4; ++r) {
                const float dist = fmaf(-2.f, c[r], e2v);
                if (dist < bd[lt][r]) { bd[lt][r] = dist; bm[lt][r] = mloc; }
            }
        }
    }

    // reduce over the 16 lanes (cols) of each group; tie -> lower m (np.argmin)
#pragma unroll
    for (int lt = 0; lt < 4; ++lt)
#pragma unroll
        for (int r = 0; r < 4; ++r) {
            float d0 = bd[lt][r];
            int m0 = bm[lt][r];
#pragma unroll
            for (int off = 1; off < 16; off <<= 1) {
                const float dn = __shfl_xor(d0, off, 64);
                const int mn = __shfl_xor(m0, off, 64);
                if (dn < d0 || (dn == d0 && mn < m0)) { d0 = dn; m0 = mn; }
            }
            bd[lt][r] = d0;
            bm[lt][r] = m0;
        }
    if (j16 == 0) {
#pragma unroll
        for (int lt = 0; lt < 4; ++lt)
#pragma unroll
            for (int r = 0; r < 4; ++r)
                sidx[w * 64 + lt * 16 + kg * 4 + r] = (unsigned short)bm[lt][r];
    }
    __syncthreads();

    // epilogue: idx write, quantized out, exact fp32 loss
    const unsigned m = sidx[tid];
    idx_out[n * NL + lbase + tid] = (unsigned short)m;
    const float* q = emb + ((size_t)n * NM + m) * ND;
    float* op = out + (size_t)b * NCHW + n * ND * NHW + hw0 + tid;
    float lacc = 0.f;
#pragma unroll
    for (int d0 = 0; d0 < ND; d0 += 4) {
        const float4 qv = *(const float4*)&q[d0];
        float xd, df;
        xd = sx[tid * XPAD + d0 + 0]; op[(d0 + 0) * NHW] = qv.x; df = xd - qv.x; lacc = fmaf(df, df, lacc);
        xd = sx[tid * XPAD + d0 + 1]; op[(d0 + 1) * NHW] = qv.y; df = xd - qv.y; lacc = fmaf(df, df, lacc);
        xd = sx[tid * XPAD + d0 + 2]; op[(d0 + 2) * NHW] = qv.z; df = xd - qv.z; lacc = fmaf(df, df, lacc);
        xd = sx[tid * XPAD + d0 + 3]; op[(d0 + 3) * NHW] = qv.w; df = xd - qv.w; lacc = fmaf(df, df, lacc);
    }
#pragma unroll
    for (int off = 32; off; off >>= 1) lacc += __shfl_down(lacc, off);
    if (lane == 0) red[w] = lacc;
    __syncthreads();
    if (tid == 0)
        atomicAdd(loss_out, (red[0] + red[1] + red[2] + red[3]) * LOSS_SCALE);
}

// ---- K3: counts/dw scatter: 512 threads, 2 points/thread, LDS accumulate,
//      one global atomic per cell on flush ----
__launch_bounds__(512, 2)
__global__ void vq_scatter(const float* __restrict__ x,
                           const unsigned short* __restrict__ idx,
                           float* __restrict__ dw, float* __restrict__ counts) {
    __shared__ float sdw[NM * XPAD]; // 67584 B
    __shared__ float scnt[NM];
    const int n = blockIdx.y;
    const int b = blockIdx.x; // one batch per block
    const int tid = threadIdx.x; // 0..511

    for (int i = tid; i < NM * XPAD; i += 512) sdw[i] = 0.f;
    if (tid < NM) scnt[tid] = 0.f;
    __syncthreads();

    const float* xp = x + (size_t)b * NCHW + n * ND * NHW;
#pragma unroll
    for (int it = 0; it < 2; ++it) {
        const int hw = it * 512 + tid;
        const unsigned m = idx[n * NL + b * NHW + hw];
        float* dst = &sdw[m * XPAD];
#pragma unroll
        for (int d = 0; d < ND; ++d)
            atomicAdd(&dst[d], xp[d * NHW + hw]);
        atomicAdd(&scnt[m], 1.0f);
    }
    __syncthreads();

    float* dwn = dw + (size_t)n * NM * ND;
    for (int i = tid; i < NM * ND; i += 512)
        atomicAdd(&dwn[i], sdw[(i >> 5) * XPAD + (i & 31)]);
    if (tid < NM) atomicAdd(&counts[n * NM + tid], scnt[tid]);
}

// ---- K4a: EMA count update + perplexity ----
__global__ void vq_update_cnt(const float* __restrict__ ema_count,
                              const float* __restrict__ counts,
                              float* __restrict__ out_cnt,
                              float* __restrict__ perp_out) {
    const int n = blockIdx.x;
    const int m = threadIdx.x; // 512
    __shared__ float r1[8], r2[8];
    __shared__ float s_ntot;

    const float cnt = counts[n * NM + m];
    const float cnew = DECAYF * ema_count[n * NM + m] + OMDF * cnt;
    const float avg = cnt / (float)NL;
    const float pterm = avg * logf(avg + 1e-10f);

    float v1 = cnew, v2 = pterm;
#pragma unroll
    for (int off = 32; off; off >>= 1) {
        v1 += __shfl_down(v1, off);
        v2 += __shfl_down(v2, off);
    }
    if ((m & 63) == 0) { r1[m >> 6] = v1; r2[m >> 6] = v2; }
    __syncthreads();
    if (m == 0) {
        float a = 0.f, bsum = 0.f;
#pragma unroll
        for (int i = 0; i < 8; ++i) { a += r1[i]; bsum += r2[i]; }
        s_ntot = a;
        atomicAdd(perp_out, expf(-bsum));
    }
    __syncthreads();
    const float ntot = s_ntot;
    out_cnt[n * NM + m] = (cnew + EPSF) / (ntot + MEPSF) * ntot;
}

// ---- K4b: EMA weight + embedding_new ----
__global__ void vq_update_w(const float* __restrict__ ema_weight,
                            const float* __restrict__ dw,
                            const float* __restrict__ out_cnt,
                            float* __restrict__ out_w,
                            float* __restrict__ out_emb) {
    const int i = blockIdx.x * 256 + threadIdx.x; // 131072
    const float wnew = DECAYF * ema_weight[i] + OMDF * dw[i];
    out_w[i] = wnew;
    out_emb[i] = wnew / out_cnt[i >> 5];
}

extern "C" void kernel_launch(void* const* d_in, const int* in_sizes, int n_in,
                              void* d_out, int out_size, void* d_ws, size_t ws_size,
                              hipStream_t stream) {
    const float* x = (const float*)d_in[0];
    const float* emb = (const float*)d_in[1];
    const float* ema_count = (const float*)d_in[2];
    const float* ema_weight = (const float*)d_in[3];
    float* out = (float*)d_out;
    char* ws = (char*)d_ws;
    float* ws_f = (float*)d_ws;

    // ws layout (bytes), total ~1.74 MB
    float* counts = ws_f;                                   // [0, 16384)
    float* dw = ws_f + 4096;                                // [16384, 540672)
    float* e2 = ws_f + 135168;                              // [540672, 557056)
    unsigned short* ehi = (unsigned short*)(ws + 557056);   // 327,680 B
    unsigned short* elo = (unsigned short*)(ws + 884736);   // 327,680 B
    unsigned short* idxp = (unsigned short*)(ws + 1212416); // 524,288 B

    // zero accumulators (buffers are re-poisoned to 0xAA before every timed launch)
    hipMemsetAsync(counts, 0, (size_t)(NN * NM + NN * NM * ND) * sizeof(float), stream);
    hipMemsetAsync(out + OUT_LOSS, 0, 2 * sizeof(float), stream);

    e_prep<<<16, 256, 0, stream>>>(emb, ehi, elo, e2);
    vq_argmin<<<dim3(NL / 256, NN), 256, 0, stream>>>(x, ehi, elo, e2, emb, out, idxp,
                                                      out + OUT_LOSS);
    vq_scatter<<<dim3(NB, NN), 512, 0, stream>>>(x, idxp, dw, counts);
    vq_update_cnt<<<NN, NM, 0, stream>>>(ema_count, counts, out + OUT_CNT, out + OUT_PERP);
    vq_update_w<<<NN * NM * ND / 256, 256, 0, stream>>>(ema_weight, dw, out + OUT_CNT,
                                                        out + OUT_EMB, out + OUT_W);
}

// Round 9
// 196.777 us; speedup vs baseline: 4.2048x; 1.0056x over previous
//
#include <hip/hip_runtime.h>
#include <cfloat>
#include <cmath>

// Problem constants
#define NB 32           // B
#define NN 8            // N codebooks
#define NM 512          // M codes
#define ND 32           // D dim
#define NHW 1024        // H*W
#define NC 256          // C = N*D
#define NCHW (NC * NHW) // 262144
#define NL (NB * NHW)   // 32768 points per codebook
#define EPAD 40         // padded bf16 row (80 B)
#define XPAD 33         // padded fp32 row for x / dw staging
#define TSTR (16 * EPAD) // shorts per 16-code tile

static constexpr float DECAYF = (float)0.999;
static constexpr float OMDF = (float)(1.0 - 0.999);
static constexpr float EPSF = 1e-5f;
static constexpr float MEPSF = (float)(512.0 * 1e-5);
static constexpr float LOSS_SCALE = (float)(0.25 / 8388608.0);

// Output layout (floats)
#define OUT_LOSS (NB * NC * NHW)         // 8388608
#define OUT_PERP (OUT_LOSS + 1)
#define OUT_EMB (OUT_PERP + 1)
#define OUT_CNT (OUT_EMB + NN * NM * ND)
#define OUT_W (OUT_CNT + NN * NM)

typedef __attribute__((ext_vector_type(8))) short bf16x8;
typedef __attribute__((ext_vector_type(4))) float f32x4;

__device__ inline unsigned short f2bf(float f) {
    unsigned u = __builtin_bit_cast(unsigned, f);
    u += 0x7FFFu + ((u >> 16) & 1u);
    return (unsigned short)(u >> 16);
}
__device__ inline float bf2f(unsigned short h) {
    unsigned u = ((unsigned)h) << 16;
    return __builtin_bit_cast(float, u);
}

// ---- K1: embedding prep: bf16 hi/lo split (padded rows) + e2 ----
__global__ void e_prep(const float* __restrict__ emb, unsigned short* __restrict__ ehi,
                       unsigned short* __restrict__ elo, float* __restrict__ e2) {
    const int i = blockIdx.x * 256 + threadIdx.x; // (n*512 + m), 4096 total
    const float* e = emb + i * ND;
    unsigned short* hi = ehi + (size_t)i * EPAD;
    unsigned short* lo = elo + (size_t)i * EPAD;
    float s = 0.f;
#pragma unroll
    for (int d = 0; d < ND; ++d) {
        const float v = e[d];
        s = fmaf(v, v, s);
        const unsigned short h = f2bf(v);
        hi[d] = h;
        lo[d] = f2bf(v - bf2f(h));
    }
    e2[i] = s;
}

// ---- K2: MFMA distances + argmin + quantized output + loss ----
// Codes read as B-fragments from global (L2-resident); 2 m-tiles per
// iteration with pair prefetch (effective 2-deep) to cover L2 latency.
__launch_bounds__(256, 4)
__global__ void vq_argmin(const float* __restrict__ x,
                          const unsigned short* __restrict__ ehi,
                          const unsigned short* __restrict__ elo,
                          const float* __restrict__ e2g,
                          const float* __restrict__ emb,
                          float* __restrict__ out,
                          unsigned short* __restrict__ idx_out,
                          float* __restrict__ loss_out) {
    __shared__ __align__(16) float sx[256 * XPAD];           // 33792 B
    __shared__ float se2[NM];                                // 2048 B
    __shared__ unsigned short sidx[256];
    __shared__ float red[4];

    const int n = blockIdx.y;
    const int lbase = blockIdx.x * 256;
    const int tid = threadIdx.x;
    const int b = lbase >> 10;
    const int hw0 = lbase & (NHW - 1);

    // stage x tile: [256 points][32 d] fp32, padded (bank-conflict-free writes)
    {
        const float* xp = x + (size_t)b * NCHW + n * ND * NHW + hw0 + tid;
#pragma unroll
        for (int d = 0; d < ND; ++d)
            sx[tid * XPAD + d] = xp[d * NHW];
    }
    for (int i = tid; i < NM; i += 256) se2[i] = e2g[n * NM + i];
    __syncthreads();

    const int lane = tid & 63;
    const int w = tid >> 6;
    const int j16 = lane & 15;   // row (A) / col (B) index
    const int kg = lane >> 4;    // k-group

    // A fragments: 4 ltiles x 8 bf16, hi/lo split
    bf16x8 ah[4], al[4];
#pragma unroll
    for (int lt = 0; lt < 4; ++lt) {
        const int row = w * 64 + lt * 16 + j16;
        const float* sr = &sx[row * XPAD + kg * 8];
#pragma unroll
        for (int j = 0; j < 8; ++j) {
            const float v = sr[j];
            const unsigned short h = f2bf(v);
            ah[lt][j] = (short)h;
            al[lt][j] = (short)f2bf(v - bf2f(h));
        }
    }

    float bd[4][4];
    int bm[4][4];
#pragma unroll
    for (int lt = 0; lt < 4; ++lt)
#pragma unroll
        for (int r = 0; r < 4; ++r) { bd[lt][r] = FLT_MAX; bm[lt][r] = 0; }

    // B-fragment base for this lane: code row (n*512 + j16), d-slice kg*8
    const unsigned short* bh_base = ehi + ((size_t)n * NM + j16) * EPAD + kg * 8;
    const unsigned short* bl_base = elo + ((size_t)n * NM + j16) * EPAD + kg * 8;

    // 2 tiles per iteration, pair prefetch (2-deep effective)
    bf16x8 bh0 = *(const bf16x8*)(bh_base);
    bf16x8 bl0 = *(const bf16x8*)(bl_base);
    bf16x8 bh1 = *(const bf16x8*)(bh_base + TSTR);
    bf16x8 bl1 = *(const bf16x8*)(bl_base + TSTR);
    for (int mt = 0; mt < 32; mt += 2) {
        const bf16x8 cbh0 = bh0, cbl0 = bl0, cbh1 = bh1, cbl1 = bl1;
        if (mt < 30) {
            bh0 = *(const bf16x8*)(bh_base + (size_t)(mt + 2) * TSTR);
            bl0 = *(const bf16x8*)(bl_base + (size_t)(mt + 2) * TSTR);
            bh1 = *(const bf16x8*)(bh_base + (size_t)(mt + 3) * TSTR);
            bl1 = *(const bf16x8*)(bl_base + (size_t)(mt + 3) * TSTR);
        }
        {
            const int mloc = mt * 16 + j16;
            const float e2v = se2[mloc];
#pragma unroll
            for (int lt = 0; lt < 4; ++lt) {
                f32x4 c = {0.f, 0.f, 0.f, 0.f};
                c = __builtin_amdgcn_mfma_f32_16x16x32_bf16(ah[lt], cbh0, c, 0, 0, 0);
                c = __builtin_amdgcn_mfma_f32_16x16x32_bf16(al[lt], cbh0, c, 0, 0, 0);
                c = __builtin_amdgcn_mfma_f32_16x16x32_bf16(ah[lt], cbl0, c, 0, 0, 0);
#pragma unroll
                for (int r = 0; r < 4; ++r) {
                    const float dist = fmaf(-2.f, c[r], e2v);
                    if (dist < bd[lt][r]) { bd[lt][r] = dist; bm[lt][r] = mloc; }
                }
            }
        }
        {
            const int mloc = (mt + 1) * 16 + j16;
            const float e2v = se2[mloc];
#pragma unroll
            for (int lt = 0; lt < 4; ++lt) {
                f32x4 c = {0.f, 0.f, 0.f, 0.f};
                c = __builtin_amdgcn_mfma_f32_16x16x32_bf16(ah[lt], cbh1, c, 0, 0, 0);
                c = __builtin_amdgcn_mfma_f32_16x16x32_bf16(al[lt], cbh1, c, 0, 0, 0);
                c = __builtin_amdgcn_mfma_f32_16x16x32_bf16(ah[lt], cbl1, c, 0, 0, 0);
#pragma unroll
                for (int r = 0; r < 4; ++r) {
                    const float dist = fmaf(-2.f, c[r], e2v);
                    if (dist < bd[lt][r]) { bd[lt][r] = dist; bm[lt][r] = mloc; }
                }
            }
        }
    }

    // reduce over the 16 lanes (cols) of each group; tie -> lower m (np.argmin)
#pragma unroll
    for (int lt = 0; lt < 4; ++lt)
#pragma unroll
        for (int r = 0; r < 4; ++r) {
            float d0 = bd[lt][r];
            int m0 = bm[lt][r];
#pragma unroll
            for (int off = 1; off < 16; off <<= 1) {
                const float dn = __shfl_xor(d0, off, 64);
                const int mn = __shfl_xor(m0, off, 64);
                if (dn < d0 || (dn == d0 && mn < m0)) { d0 = dn; m0 = mn; }
            }
            bd[lt][r] = d0;
            bm[lt][r] = m0;
        }
    if (j16 == 0) {
#pragma unroll
        for (int lt = 0; lt < 4; ++lt)
#pragma unroll
            for (int r = 0; r < 4; ++r)
                sidx[w * 64 + lt * 16 + kg * 4 + r] = (unsigned short)bm[lt][r];
    }
    __syncthreads();

    // epilogue: idx write, quantized out, exact fp32 loss
    const unsigned m = sidx[tid];
    idx_out[n * NL + lbase + tid] = (unsigned short)m;
    const float* q = emb + ((size_t)n * NM + m) * ND;
    float* op = out + (size_t)b * NCHW + n * ND * NHW + hw0 + tid;
    float lacc = 0.f;
#pragma unroll
    for (int d0 = 0; d0 < ND; d0 += 4) {
        const float4 qv = *(const float4*)&q[d0];
        float xd, df;
        xd = sx[tid * XPAD + d0 + 0]; op[(d0 + 0) * NHW] = qv.x; df = xd - qv.x; lacc = fmaf(df, df, lacc);
        xd = sx[tid * XPAD + d0 + 1]; op[(d0 + 1) * NHW] = qv.y; df = xd - qv.y; lacc = fmaf(df, df, lacc);
        xd = sx[tid * XPAD + d0 + 2]; op[(d0 + 2) * NHW] = qv.z; df = xd - qv.z; lacc = fmaf(df, df, lacc);
        xd = sx[tid * XPAD + d0 + 3]; op[(d0 + 3) * NHW] = qv.w; df = xd - qv.w; lacc = fmaf(df, df, lacc);
    }
#pragma unroll
    for (int off = 32; off; off >>= 1) lacc += __shfl_down(lacc, off);
    if (lane == 0) red[w] = lacc;
    __syncthreads();
    if (tid == 0)
        atomicAdd(loss_out, (red[0] + red[1] + red[2] + red[3]) * LOSS_SCALE);
}

// ---- K3: counts/dw scatter: LDS accumulate, flush to one of `copies`
//      partial buffers (contention / copies) ----
__launch_bounds__(512, 2)
__global__ void vq_scatter(const float* __restrict__ x,
                           const unsigned short* __restrict__ idx,
                           float* __restrict__ pdw, float* __restrict__ pcnt,
                           int copy_mask) {
    __shared__ float sdw[NM * XPAD]; // 67584 B
    __shared__ float scnt[NM];
    const int n = blockIdx.y;
    const int b = blockIdx.x; // one batch per block
    const int tid = threadIdx.x; // 0..511
    const int copy = b & copy_mask;

    for (int i = tid; i < NM * XPAD; i += 512) sdw[i] = 0.f;
    if (tid < NM) scnt[tid] = 0.f;
    __syncthreads();

    const float* xp = x + (size_t)b * NCHW + n * ND * NHW;
#pragma unroll
    for (int it = 0; it < 2; ++it) {
        const int hw = it * 512 + tid;
        const unsigned m = idx[n * NL + b * NHW + hw];
        float* dst = &sdw[m * XPAD];
#pragma unroll
        for (int d = 0; d < ND; ++d)
            atomicAdd(&dst[d], xp[d * NHW + hw]);
        atomicAdd(&scnt[m], 1.0f);
    }
    __syncthreads();

    float* dwn = pdw + (size_t)copy * (NN * NM * ND) + (size_t)n * NM * ND;
    for (int i = tid; i < NM * ND; i += 512)
        atomicAdd(&dwn[i], sdw[(i >> 5) * XPAD + (i & 31)]);
    float* cn = pcnt + (size_t)copy * (NN * NM) + n * NM;
    if (tid < NM) atomicAdd(&cn[tid], scnt[tid]);
}

// ---- K4a: reduce copies + EMA count update + perplexity ----
__global__ void vq_update_cnt(const float* __restrict__ ema_count,
                              const float* __restrict__ pcnt,
                              float* __restrict__ out_cnt,
                              float* __restrict__ perp_out, int copies) {
    const int n = blockIdx.x;
    const int m = threadIdx.x; // 512
    __shared__ float r1[8], r2[8];
    __shared__ float s_ntot;

    float cnt = 0.f;
    for (int c = 0; c < copies; ++c)
        cnt += pcnt[(size_t)c * (NN * NM) + n * NM + m];

    const float cnew = DECAYF * ema_count[n * NM + m] + OMDF * cnt;
    const float avg = cnt / (float)NL;
    const float pterm = avg * logf(avg + 1e-10f);

    float v1 = cnew, v2 = pterm;
#pragma unroll
    for (int off = 32; off; off >>= 1) {
        v1 += __shfl_down(v1, off);
        v2 += __shfl_down(v2, off);
    }
    if ((m & 63) == 0) { r1[m >> 6] = v1; r2[m >> 6] = v2; }
    __syncthreads();
    if (m == 0) {
        float a = 0.f, bsum = 0.f;
#pragma unroll
        for (int i = 0; i < 8; ++i) { a += r1[i]; bsum += r2[i]; }
        s_ntot = a;
        atomicAdd(perp_out, expf(-bsum));
    }
    __syncthreads();
    const float ntot = s_ntot;
    out_cnt[n * NM + m] = (cnew + EPSF) / (ntot + MEPSF) * ntot;
}

// ---- K4b: reduce copies + EMA weight + embedding_new ----
__global__ void vq_update_w(const float* __restrict__ ema_weight,
                            const float* __restrict__ pdw,
                            const float* __restrict__ out_cnt,
                            float* __restrict__ out_w,
                            float* __restrict__ out_emb, int copies) {
    const int i = blockIdx.x * 512 + threadIdx.x; // 131072
    float dw = 0.f;
    for (int c = 0; c < copies; ++c)
        dw += pdw[(size_t)c * (NN * NM * ND) + i];
    const float wnew = DECAYF * ema_weight[i] + OMDF * dw;
    out_w[i] = wnew;
    out_emb[i] = wnew / out_cnt[i >> 5];
}

extern "C" void kernel_launch(void* const* d_in, const int* in_sizes, int n_in,
                              void* d_out, int out_size, void* d_ws, size_t ws_size,
                              hipStream_t stream) {
    const float* x = (const float*)d_in[0];
    const float* emb = (const float*)d_in[1];
    const float* ema_count = (const float*)d_in[2];
    const float* ema_weight = (const float*)d_in[3];
    float* out = (float*)d_out;
    char* ws = (char*)d_ws;

    // choose partial-copy count from scratch size (ws_size is call-invariant)
    const size_t rest_bytes = 16384 + 327680 + 327680 + 524288; // e2, ehi, elo, idx
    const size_t per_copy = (size_t)(NN * NM + NN * NM * ND) * 4; // 540672
    int copies = (ws_size >= 8 * per_copy + rest_bytes) ? 8 : 1;

    float* pcnt = (float*)ws;                                   // copies * 16384 B
    float* pdw = (float*)(ws + (size_t)copies * NN * NM * 4);   // copies * 524288 B
    char* restp = ws + (size_t)copies * per_copy;
    float* e2 = (float*)restp;
    unsigned short* ehi = (unsigned short*)(restp + 16384);
    unsigned short* elo = (unsigned short*)(restp + 16384 + 327680);
    unsigned short* idxp = (unsigned short*)(restp + 16384 + 655360);

    // zero accumulators (buffers are re-poisoned to 0xAA before every timed launch)
    hipMemsetAsync(ws, 0, (size_t)copies * per_copy, stream);
    hipMemsetAsync(out + OUT_LOSS, 0, 2 * sizeof(float), stream);

    e_prep<<<16, 256, 0, stream>>>(emb, ehi, elo, e2);
    vq_argmin<<<dim3(NL / 256, NN), 256, 0, stream>>>(x, ehi, elo, e2, emb, out, idxp,
                                                      out + OUT_LOSS);
    vq_scatter<<<dim3(NB, NN), 512, 0, stream>>>(x, idxp, pdw, pcnt, copies - 1);
    vq_update_cnt<<<NN, NM, 0, stream>>>(ema_count, pcnt, out + OUT_CNT, out + OUT_PERP,
                                         copies);
    vq_update_w<<<NN * NM * ND / 512, 512, 0, stream>>>(ema_weight, pdw, out + OUT_CNT,
                                                        out + OUT_EMB, out + OUT_W, copies);
}